// Round 8
// baseline (408.383 us; speedup 1.0000x reference)
//
#include <hip/hip_runtime.h>
#include <cstdint>

// Self-attention, B=2 S=2048 D=1024 H=16 hd=64, fp32 in/out, bf16 MFMA internals.
// Pipeline: convert -> fused QKV GEMM (K pre-scaled by 0.125*log2e; V stored
// transposed [B,H,d,S] with key-bit-permuted columns) -> flash attention
// (S^T orientation, no-max softmax, key-parallel waves, in-register P^T,
// b128 V fragments) -> output GEMM (128x128).

typedef unsigned short ush;
typedef __bf16 bf16x8 __attribute__((ext_vector_type(8)));
typedef float f32x4 __attribute__((ext_vector_type(4)));
typedef ush u16x8 __attribute__((ext_vector_type(8)));
typedef ush u16x4 __attribute__((ext_vector_type(4)));
typedef unsigned int u32x4 __attribute__((ext_vector_type(4)));

__device__ __forceinline__ ush f2bf(float f) {
  unsigned int u = __float_as_uint(f);
  u += 0x7fffu + ((u >> 16) & 1u);   // RNE
  return (ush)(u >> 16);
}

// pack bf16(b)<<16 | bf16(a), round-half-up, 3 VALU ops
__device__ __forceinline__ unsigned int pack2bf_ru(float a, float b) {
  unsigned int ua = __float_as_uint(a) + 0x8000u;
  unsigned int ub = __float_as_uint(b) + 0x8000u;
  return __builtin_amdgcn_perm(ub, ua, 0x07060302u);
}

__device__ __forceinline__ bf16x8 bc8(u16x8 v) {
  return __builtin_bit_cast(bf16x8, v);
}

// async 16B global->LDS (DMA, wave-uniform LDS base + lane*16)
__device__ __forceinline__ void async16(const void* g, void* l) {
  __builtin_amdgcn_global_load_lds(
      (const __attribute__((address_space(1))) unsigned int*)(uintptr_t)g,
      (__attribute__((address_space(3))) unsigned int*)(uintptr_t)l, 16, 0, 0);
}

// ---------------- convert fp32 -> bf16 (x + 4 weights) ----------------
__global__ __launch_bounds__(256) void convert_kernel(
    const float* __restrict__ x, const float* __restrict__ Wq,
    const float* __restrict__ Wk, const float* __restrict__ Wv,
    const float* __restrict__ Wo,
    ush* __restrict__ xb, ush* __restrict__ Wqb, ush* __restrict__ Wkb,
    ush* __restrict__ Wvb, ush* __restrict__ Wob)
{
  int tid = blockIdx.x * 256 + threadIdx.x;
  int base = tid * 4;
  const float* src; ush* dst; int idx;
  if (base < 4194304) { src = x; dst = xb; idx = base; }
  else {
    int r = base - 4194304;
    int seg = r >> 20;
    idx = r & 1048575;
    src = seg == 0 ? Wq : seg == 1 ? Wk : seg == 2 ? Wv : Wo;
    dst = seg == 0 ? Wqb : seg == 1 ? Wkb : seg == 2 ? Wvb : Wob;
  }
  float4 f = *(const float4*)(src + idx);
  u16x4 u = { f2bf(f.x), f2bf(f.y), f2bf(f.z), f2bf(f.w) };
  *(u16x4*)(dst + idx) = u;
}

// ---------------- 128x128 NT bf16 GEMM core, K=1024, BK=64 ----------------
__device__ __forceinline__ void gemm128_core(
    const ush* __restrict__ gA, const ush* __restrict__ gB,
    int m0, int n0, ush* lA, ush* lB, f32x4 (&acc)[4][4])
{
  const int t = threadIdx.x, w = t >> 6, lane = t & 63;
  const int l15 = lane & 15, quad = lane >> 4;
  const int wm = (w >> 1) * 64, wn = (w & 1) * 64;
#pragma unroll
  for (int i = 0; i < 4; ++i)
#pragma unroll
    for (int j = 0; j < 4; ++j) acc[i][j] = (f32x4){0.f, 0.f, 0.f, 0.f};

  for (int kt = 0; kt < 1024; kt += 64) {
#pragma unroll
    for (int i = 0; i < 4; ++i) {           // A tile: 128x64 = 1024 chunks
      int j = i * 256 + w * 64 + lane;
      int row = j >> 3, cc = (j & 7) ^ (row & 7);
      async16(gA + (size_t)(m0 + row) * 1024 + kt + cc * 8,
              lA + (i * 256 + w * 64) * 8);
    }
#pragma unroll
    for (int i = 0; i < 4; ++i) {           // B tile
      int j = i * 256 + w * 64 + lane;
      int row = j >> 3, cc = (j & 7) ^ (row & 7);
      async16(gB + (size_t)(n0 + row) * 1024 + kt + cc * 8,
              lB + (i * 256 + w * 64) * 8);
    }
    __syncthreads();
#pragma unroll
    for (int kf = 0; kf < 2; ++kf) {
      bf16x8 aF[4], bF[4];
#pragma unroll
      for (int mt = 0; mt < 4; ++mt) {
        int row = wm + mt * 16 + l15;
        aF[mt] = bc8(*(const u16x8*)(lA + row * 64 + (((kf * 4 + quad) ^ (row & 7)) * 8)));
      }
#pragma unroll
      for (int nt = 0; nt < 4; ++nt) {
        int row = wn + nt * 16 + l15;
        bF[nt] = bc8(*(const u16x8*)(lB + row * 64 + (((kf * 4 + quad) ^ (row & 7)) * 8)));
      }
#pragma unroll
      for (int mt = 0; mt < 4; ++mt)
#pragma unroll
        for (int nt = 0; nt < 4; ++nt)
          acc[mt][nt] = __builtin_amdgcn_mfma_f32_16x16x32_bf16(
              aF[mt], bF[nt], acc[mt][nt], 0, 0, 0);
    }
    __syncthreads();
  }
}

// ---------------- fused QKV projection ----------------
// grid = 3 * 256 blocks. Q,K as [B,H,S,64]; V transposed as [B,H,64,S] with
// columns permuted within each 64-token window: p = [s5][s3][s2][s4][s1][s0]
// so the attention PV A-fragment is one contiguous 16B LDS read.
// K output pre-scaled by 0.125*log2(e) so attention scores feed exp2 raw.
__global__ __launch_bounds__(256, 2) void qkv_gemm(
    const ush* __restrict__ xb, const ush* __restrict__ Wqb,
    const ush* __restrict__ Wkb, const ush* __restrict__ Wvb,
    const float* __restrict__ bq, const float* __restrict__ bk,
    const float* __restrict__ bv,
    ush* __restrict__ q, ush* __restrict__ k, ush* __restrict__ vt)
{
  int bid = blockIdx.x;
  int wsel = bid >> 8;
  int rem = bid & 255;
  int m0 = (rem & 31) * 128;
  int n0 = (rem >> 5) * 128;
  const ush* gB = wsel == 0 ? Wqb : wsel == 1 ? Wkb : Wvb;
  const float* bias = wsel == 0 ? bq : wsel == 1 ? bk : bv;
  const float oscale = wsel == 1 ? 0.180336880f : 1.0f;  // 0.125*log2e on K

  __shared__ alignas(16) ush lA[128 * 64];
  __shared__ alignas(16) ush lB[128 * 64];
  f32x4 acc[4][4];
  gemm128_core(xb, gB, m0, n0, lA, lB, acc);

  const int t = threadIdx.x, w = t >> 6, lane = t & 63;
  const int l15 = lane & 15, quad = lane >> 4;
  const int wm = (w >> 1) * 64, wn = (w & 1) * 64;
  if (wsel == 2) {
    // V^T with permuted column order; 4 consecutive s -> 4 consecutive p
#pragma unroll
    for (int nt = 0; nt < 4; ++nt) {
      int o = n0 + wn + nt * 16 + l15;
      float bl = bias[o];
      int h = o >> 6, d = o & 63;
#pragma unroll
      for (int mt = 0; mt < 4; ++mt) {
        int tb = m0 + wm + mt * 16 + quad * 4;
        int b = tb >> 11, s = tb & 2047;
        int so = s & 63;
        int sp = (s & ~63) | (so & 35) | ((so & 12) << 1) | ((so & 16) >> 2);
        u16x4 pk = { f2bf(acc[mt][nt][0] + bl), f2bf(acc[mt][nt][1] + bl),
                     f2bf(acc[mt][nt][2] + bl), f2bf(acc[mt][nt][3] + bl) };
        *(u16x4*)(vt + (size_t)(((b * 16 + h) * 64) + d) * 2048 + sp) = pk;
      }
    }
  } else {
    ush* dst = wsel == 0 ? q : k;
#pragma unroll
    for (int nt = 0; nt < 4; ++nt) {
      int o = n0 + wn + nt * 16 + l15;
      float bl = bias[o];
      int h = o >> 6, d = o & 63;
#pragma unroll
      for (int mt = 0; mt < 4; ++mt)
#pragma unroll
        for (int r = 0; r < 4; ++r) {
          int token = m0 + wm + mt * 16 + quad * 4 + r;
          int b = token >> 11, s = token & 2047;
          dst[(size_t)(((b * 16 + h) * 2048) + s) * 64 + d] =
              f2bf((acc[mt][nt][r] + bl) * oscale);
        }
    }
  }
}

// ---------------- flash attention (key-parallel waves) ----------------
// 1024 blocks = 32 bh x 32 q-tiles of 64 rows; 2 waves. Each wave handles
// HALF the keys (wave w <-> keys [32w,32w+32) of each staged tile) for ALL
// four 16-query groups -> per-wave LDS reads halve vs query-split. The
// no-max softmax is linear, so li/accO are plain sums: cross-wave reduction
// once at kernel end through LDS. Block swizzle keeps one bh per XCD.
__global__ __launch_bounds__(128, 2) void attn_kernel(
    const ush* __restrict__ Q, const ush* __restrict__ K,
    const ush* __restrict__ VT, ush* __restrict__ O)
{
  const int bid = blockIdx.x;
  const int bh = (bid & 7) * 4 + (bid >> 8);   // same bh -> same XCD residue
  const int qt = (bid >> 3) & 31;
  const ush* qb = Q + (size_t)bh * 2048 * 64;
  const ush* kb = K + (size_t)bh * 2048 * 64;
  const ush* vtb = VT + (size_t)bh * 64 * 2048;   // [d][p(s)]
  const int t = threadIdx.x, w = t >> 6, lane = t & 63;
  const int l15 = lane & 15, quad = lane >> 4;
  const int q0 = qt * 64;                 // block's 64 queries (4 groups)

  __shared__ alignas(16) ush lK[2][64 * 64];     // [key][d], swizzled chunks
  __shared__ alignas(16) ush lV[2][64 * 64];     // [d][p(key)], swizzled chunks

  // staging: 512 chunks per tensor, 128 threads -> 4 chunks each.
  const int r0 = t >> 3;
  const int c0 = (t & 7) ^ (r0 & 7);
  const ush* kSrc = kb + (size_t)r0 * 64 + c0 * 8;      // +i*1024
  const ush* vSrc = vtb + (size_t)r0 * 2048 + c0 * 8;   // +i*16*2048

  // Q fragments (B-operand: n=q=l15, k=d), 4 groups x 2 kf
  bf16x8 qF[4][2];
#pragma unroll
  for (int g = 0; g < 4; ++g)
#pragma unroll
    for (int kf = 0; kf < 2; ++kf)
      qF[g][kf] = bc8(*(const u16x8*)(qb + (size_t)(q0 + g * 16 + l15) * 64 +
                                      kf * 32 + quad * 8));

  float li[4] = {0.f, 0.f, 0.f, 0.f};
  f32x4 accO[4][4];                       // O^T partial: [d][q], keys of wave w
#pragma unroll
  for (int g = 0; g < 4; ++g)
#pragma unroll
    for (int dt = 0; dt < 4; ++dt) accO[g][dt] = (f32x4){0.f, 0.f, 0.f, 0.f};

  // prologue: DMA tile 0 into buffer 0
#pragma unroll
  for (int i = 0; i < 4; ++i) {
    async16(kSrc + i * 1024, lK[0] + (i * 128 + t) * 8);
    async16(vSrc + (size_t)i * 16 * 2048, lV[0] + (i * 128 + t) * 8);
  }
  __syncthreads();                       // vmcnt drain = DMA complete

  for (int it = 0; it < 32; ++it) {
    const int cur = it & 1, nxt = cur ^ 1;
    if (it + 1 < 32) {                   // DMA next tile while computing this one
      const size_t ko = (size_t)(it + 1) * 64 * 64;   // K advances by rows
      const int vo = (it + 1) * 64;                   // V^T advances by cols
#pragma unroll
      for (int i = 0; i < 4; ++i) {
        async16(kSrc + ko + i * 1024, lK[nxt] + (i * 128 + t) * 8);
        async16(vSrc + vo + (size_t)i * 16 * 2048, lV[nxt] + (i * 128 + t) * 8);
      }
    }
    const ush* lk = lK[cur];
    const ush* lv = lV[cur];

    // S^T = K·Q^T, this wave's 32 keys: rows (2w+mt')*16+l15
    f32x4 sc[4][2];
#pragma unroll
    for (int g = 0; g < 4; ++g)
#pragma unroll
      for (int mt = 0; mt < 2; ++mt) sc[g][mt] = (f32x4){0.f, 0.f, 0.f, 0.f};
#pragma unroll
    for (int kf = 0; kf < 2; ++kf) {
#pragma unroll
      for (int mt = 0; mt < 2; ++mt) {
        int row = (2 * w + mt) * 16 + l15;
        bf16x8 aK = bc8(*(const u16x8*)(lk + row * 64 + (((kf * 4 + quad) ^ (row & 7)) * 8)));
#pragma unroll
        for (int g = 0; g < 4; ++g)
          sc[g][mt] = __builtin_amdgcn_mfma_f32_16x16x32_bf16(
              aK, qF[g][kf], sc[g][mt], 0, 0, 0);
      }
    }

    // softmax partials: raw v_exp (args bounded; K pre-scaled)
#pragma unroll
    for (int g = 0; g < 4; ++g) {
      float rs = 0.f;
#pragma unroll
      for (int mt = 0; mt < 2; ++mt)
#pragma unroll
        for (int r = 0; r < 4; ++r) {
          sc[g][mt][r] = __builtin_amdgcn_exp2f(sc[g][mt][r]);
          rs += sc[g][mt][r];
        }
      rs += __shfl_xor(rs, 16);
      rs += __shfl_xor(rs, 32);
      li[g] += rs;
    }

    // PV over this wave's key window (ks = w): A = V (contiguous b128 thanks
    // to the storage permutation), B = packed exps (in-register P^T).
    bf16x8 aV[4];
#pragma unroll
    for (int dt = 0; dt < 4; ++dt)
      aV[dt] = bc8(*(const u16x8*)(lv + (dt * 16 + l15) * 64 +
                                   (((w * 4 + quad) ^ (l15 & 7)) * 8)));
#pragma unroll
    for (int g = 0; g < 4; ++g) {
      u32x4 bw = { pack2bf_ru(sc[g][0][0], sc[g][0][1]),
                   pack2bf_ru(sc[g][0][2], sc[g][0][3]),
                   pack2bf_ru(sc[g][1][0], sc[g][1][1]),
                   pack2bf_ru(sc[g][1][2], sc[g][1][3]) };
      bf16x8 bP = __builtin_bit_cast(bf16x8, bw);
#pragma unroll
      for (int dt = 0; dt < 4; ++dt)
        accO[g][dt] = __builtin_amdgcn_mfma_f32_16x16x32_bf16(
            aV[dt], bP, accO[g][dt], 0, 0, 0);
    }
    __syncthreads();   // all reads of cur done + next-tile DMA drained
  }

  // cross-wave reduction: wave w owns output groups {2w, 2w+1}; exchange the
  // foreign-group partials through LDS (staging buffers are dead now).
  float* redO = (float*)lK;              // [w][j][dt][lane] f32x4 -> 16 KB
  float* redL = (float*)lV;              // [w][j][lane] float
  const int ow = 1 - w;
#pragma unroll
  for (int j = 0; j < 2; ++j) {
    int fg = ow * 2 + j;                 // foreign group, owned by other wave
#pragma unroll
    for (int dt = 0; dt < 4; ++dt)
      *(f32x4*)(redO + (((w * 2 + j) * 4 + dt) * 64 + lane) * 4) = accO[fg][dt];
    redL[(w * 2 + j) * 64 + lane] = li[fg];
  }
  __syncthreads();
  const int b = bh >> 4, h = bh & 15;
#pragma unroll
  for (int j = 0; j < 2; ++j) {
    int mg = w * 2 + j;                  // my group
#pragma unroll
    for (int dt = 0; dt < 4; ++dt)
      accO[mg][dt] += *(const f32x4*)(redO + (((ow * 2 + j) * 4 + dt) * 64 + lane) * 4);
    float lsum = li[mg] + redL[(ow * 2 + j) * 64 + lane];
    const float linv = __builtin_amdgcn_rcpf(lsum);
    const int s = q0 + mg * 16 + l15;
#pragma unroll
    for (int dt = 0; dt < 4; ++dt) {
      u16x4 pk = { f2bf(accO[mg][dt][0] * linv), f2bf(accO[mg][dt][1] * linv),
                   f2bf(accO[mg][dt][2] * linv), f2bf(accO[mg][dt][3] * linv) };
      *(u16x4*)(O + (size_t)(b * 2048 + s) * 1024 + h * 64 + dt * 16 + quad * 4) = pk;
    }
  }
}

// ---------------- output projection (fp32 out) ----------------
__global__ __launch_bounds__(256, 2) void out_gemm(
    const ush* __restrict__ ab, const ush* __restrict__ Wob,
    const float* __restrict__ bo, float* __restrict__ out)
{
  int rem = blockIdx.x;
  int m0 = (rem & 31) * 128;
  int n0 = (rem >> 5) * 128;
  __shared__ alignas(16) ush lA[128 * 64];
  __shared__ alignas(16) ush lB[128 * 64];
  f32x4 acc[4][4];
  gemm128_core(ab, Wob, m0, n0, lA, lB, acc);

  const int t = threadIdx.x, w = t >> 6, lane = t & 63;
  const int l15 = lane & 15, quad = lane >> 4;
  const int wm = (w >> 1) * 64, wn = (w & 1) * 64;
#pragma unroll
  for (int nt = 0; nt < 4; ++nt) {
    int o = n0 + wn + nt * 16 + l15;
    float bl = bo[o];
#pragma unroll
    for (int mt = 0; mt < 4; ++mt)
#pragma unroll
      for (int r = 0; r < 4; ++r) {
        int token = m0 + wm + mt * 16 + quad * 4 + r;
        out[(size_t)token * 1024 + o] = acc[mt][nt][r] + bl;
      }
  }
}

extern "C" void kernel_launch(void* const* d_in, const int* in_sizes, int n_in,
                              void* d_out, int out_size, void* d_ws, size_t ws_size,
                              hipStream_t stream)
{
  const float* x  = (const float*)d_in[0];
  const float* Wq = (const float*)d_in[1];
  const float* bq = (const float*)d_in[2];
  const float* Wk = (const float*)d_in[3];
  const float* bk = (const float*)d_in[4];
  const float* Wv = (const float*)d_in[5];
  const float* bv = (const float*)d_in[6];
  const float* Wo = (const float*)d_in[7];
  const float* bo = (const float*)d_in[8];
  float* out = (float*)d_out;

  char* ws = (char*)d_ws;
  ush* xb  = (ush*)(ws);                      // 8 MiB  [4096 x 1024]
  ush* Wqb = (ush*)(ws + (size_t)( 8u << 20));// 2 MiB each
  ush* Wkb = (ush*)(ws + (size_t)(10u << 20));
  ush* Wvb = (ush*)(ws + (size_t)(12u << 20));
  ush* Wob = (ush*)(ws + (size_t)(14u << 20));
  ush* qb  = (ush*)(ws + (size_t)(16u << 20));// 8 MiB [B,H,S,64]
  ush* kb  = (ush*)(ws + (size_t)(24u << 20));
  ush* vtb = (ush*)(ws + (size_t)(32u << 20));// 8 MiB [B,H,64,S] perm cols
  ush* ab  = (ush*)(ws + (size_t)(40u << 20));// 8 MiB [B,S,D] attn out (bf16)

  convert_kernel<<<8192, 256, 0, stream>>>(x, Wq, Wk, Wv, Wo,
                                           xb, Wqb, Wkb, Wvb, Wob);
  qkv_gemm<<<768, 256, 0, stream>>>(xb, Wqb, Wkb, Wvb, bq, bk, bv, qb, kb, vtb);
  attn_kernel<<<1024, 128, 0, stream>>>(qb, kb, vtb, ab);
  out_gemm<<<256, 256, 0, stream>>>(ab, Wob, bo, out);
}

// Round 9
// 186.098 us; speedup vs baseline: 2.1944x; 2.1944x over previous
//
#include <hip/hip_runtime.h>
#include <cstdint>

// Self-attention, B=2 S=2048 D=1024 H=16 hd=64, fp32 in/out, bf16 MFMA internals.
// Pipeline: convert -> fused QKV GEMM (K pre-scaled by 0.125*log2e; V stored
// transposed [B,H,d,S] with key-bit-permuted columns) -> flash attention
// (S^T orientation, no-max softmax, key-parallel waves, in-register P^T,
// b128 V fragments; STATIC register indexing only) -> output GEMM (128x128).

typedef unsigned short ush;
typedef __bf16 bf16x8 __attribute__((ext_vector_type(8)));
typedef float f32x4 __attribute__((ext_vector_type(4)));
typedef ush u16x8 __attribute__((ext_vector_type(8)));
typedef ush u16x4 __attribute__((ext_vector_type(4)));
typedef unsigned int u32x4 __attribute__((ext_vector_type(4)));

__device__ __forceinline__ ush f2bf(float f) {
  unsigned int u = __float_as_uint(f);
  u += 0x7fffu + ((u >> 16) & 1u);   // RNE
  return (ush)(u >> 16);
}

// pack bf16(b)<<16 | bf16(a), round-half-up, 3 VALU ops
__device__ __forceinline__ unsigned int pack2bf_ru(float a, float b) {
  unsigned int ua = __float_as_uint(a) + 0x8000u;
  unsigned int ub = __float_as_uint(b) + 0x8000u;
  return __builtin_amdgcn_perm(ub, ua, 0x07060302u);
}

__device__ __forceinline__ bf16x8 bc8(u16x8 v) {
  return __builtin_bit_cast(bf16x8, v);
}

// async 16B global->LDS (DMA, wave-uniform LDS base + lane*16)
__device__ __forceinline__ void async16(const void* g, void* l) {
  __builtin_amdgcn_global_load_lds(
      (const __attribute__((address_space(1))) unsigned int*)(uintptr_t)g,
      (__attribute__((address_space(3))) unsigned int*)(uintptr_t)l, 16, 0, 0);
}

// ---------------- convert fp32 -> bf16 (x + 4 weights) ----------------
__global__ __launch_bounds__(256) void convert_kernel(
    const float* __restrict__ x, const float* __restrict__ Wq,
    const float* __restrict__ Wk, const float* __restrict__ Wv,
    const float* __restrict__ Wo,
    ush* __restrict__ xb, ush* __restrict__ Wqb, ush* __restrict__ Wkb,
    ush* __restrict__ Wvb, ush* __restrict__ Wob)
{
  int tid = blockIdx.x * 256 + threadIdx.x;
  int base = tid * 4;
  const float* src; ush* dst; int idx;
  if (base < 4194304) { src = x; dst = xb; idx = base; }
  else {
    int r = base - 4194304;
    int seg = r >> 20;
    idx = r & 1048575;
    src = seg == 0 ? Wq : seg == 1 ? Wk : seg == 2 ? Wv : Wo;
    dst = seg == 0 ? Wqb : seg == 1 ? Wkb : seg == 2 ? Wvb : Wob;
  }
  float4 f = *(const float4*)(src + idx);
  u16x4 u = { f2bf(f.x), f2bf(f.y), f2bf(f.z), f2bf(f.w) };
  *(u16x4*)(dst + idx) = u;
}

// ---------------- 128x128 NT bf16 GEMM core, K=1024, BK=64 ----------------
__device__ __forceinline__ void gemm128_core(
    const ush* __restrict__ gA, const ush* __restrict__ gB,
    int m0, int n0, ush* lA, ush* lB, f32x4 (&acc)[4][4])
{
  const int t = threadIdx.x, w = t >> 6, lane = t & 63;
  const int l15 = lane & 15, quad = lane >> 4;
  const int wm = (w >> 1) * 64, wn = (w & 1) * 64;
#pragma unroll
  for (int i = 0; i < 4; ++i)
#pragma unroll
    for (int j = 0; j < 4; ++j) acc[i][j] = (f32x4){0.f, 0.f, 0.f, 0.f};

  for (int kt = 0; kt < 1024; kt += 64) {
#pragma unroll
    for (int i = 0; i < 4; ++i) {           // A tile: 128x64 = 1024 chunks
      int j = i * 256 + w * 64 + lane;
      int row = j >> 3, cc = (j & 7) ^ (row & 7);
      async16(gA + (size_t)(m0 + row) * 1024 + kt + cc * 8,
              lA + (i * 256 + w * 64) * 8);
    }
#pragma unroll
    for (int i = 0; i < 4; ++i) {           // B tile
      int j = i * 256 + w * 64 + lane;
      int row = j >> 3, cc = (j & 7) ^ (row & 7);
      async16(gB + (size_t)(n0 + row) * 1024 + kt + cc * 8,
              lB + (i * 256 + w * 64) * 8);
    }
    __syncthreads();
#pragma unroll
    for (int kf = 0; kf < 2; ++kf) {
      bf16x8 aF[4], bF[4];
#pragma unroll
      for (int mt = 0; mt < 4; ++mt) {
        int row = wm + mt * 16 + l15;
        aF[mt] = bc8(*(const u16x8*)(lA + row * 64 + (((kf * 4 + quad) ^ (row & 7)) * 8)));
      }
#pragma unroll
      for (int nt = 0; nt < 4; ++nt) {
        int row = wn + nt * 16 + l15;
        bF[nt] = bc8(*(const u16x8*)(lB + row * 64 + (((kf * 4 + quad) ^ (row & 7)) * 8)));
      }
#pragma unroll
      for (int mt = 0; mt < 4; ++mt)
#pragma unroll
        for (int nt = 0; nt < 4; ++nt)
          acc[mt][nt] = __builtin_amdgcn_mfma_f32_16x16x32_bf16(
              aF[mt], bF[nt], acc[mt][nt], 0, 0, 0);
    }
    __syncthreads();
  }
}

// ---------------- fused QKV projection ----------------
// grid = 3 * 256 blocks. Q,K as [B,H,S,64]; V transposed as [B,H,64,S] with
// columns permuted within each 64-token window: p = [s5][s3][s2][s4][s1][s0]
// so the attention PV A-fragment is one contiguous 16B LDS read.
// K output pre-scaled by 0.125*log2(e) so attention scores feed exp2 raw.
__global__ __launch_bounds__(256, 2) void qkv_gemm(
    const ush* __restrict__ xb, const ush* __restrict__ Wqb,
    const ush* __restrict__ Wkb, const ush* __restrict__ Wvb,
    const float* __restrict__ bq, const float* __restrict__ bk,
    const float* __restrict__ bv,
    ush* __restrict__ q, ush* __restrict__ k, ush* __restrict__ vt)
{
  int bid = blockIdx.x;
  int wsel = bid >> 8;
  int rem = bid & 255;
  int m0 = (rem & 31) * 128;
  int n0 = (rem >> 5) * 128;
  const ush* gB = wsel == 0 ? Wqb : wsel == 1 ? Wkb : Wvb;
  const float* bias = wsel == 0 ? bq : wsel == 1 ? bk : bv;
  const float oscale = wsel == 1 ? 0.180336880f : 1.0f;  // 0.125*log2e on K

  __shared__ alignas(16) ush lA[128 * 64];
  __shared__ alignas(16) ush lB[128 * 64];
  f32x4 acc[4][4];
  gemm128_core(xb, gB, m0, n0, lA, lB, acc);

  const int t = threadIdx.x, w = t >> 6, lane = t & 63;
  const int l15 = lane & 15, quad = lane >> 4;
  const int wm = (w >> 1) * 64, wn = (w & 1) * 64;
  if (wsel == 2) {
    // V^T with permuted column order; 4 consecutive s -> 4 consecutive p
#pragma unroll
    for (int nt = 0; nt < 4; ++nt) {
      int o = n0 + wn + nt * 16 + l15;
      float bl = bias[o];
      int h = o >> 6, d = o & 63;
#pragma unroll
      for (int mt = 0; mt < 4; ++mt) {
        int tb = m0 + wm + mt * 16 + quad * 4;
        int b = tb >> 11, s = tb & 2047;
        int so = s & 63;
        int sp = (s & ~63) | (so & 35) | ((so & 12) << 1) | ((so & 16) >> 2);
        u16x4 pk = { f2bf(acc[mt][nt][0] + bl), f2bf(acc[mt][nt][1] + bl),
                     f2bf(acc[mt][nt][2] + bl), f2bf(acc[mt][nt][3] + bl) };
        *(u16x4*)(vt + (size_t)(((b * 16 + h) * 64) + d) * 2048 + sp) = pk;
      }
    }
  } else {
    ush* dst = wsel == 0 ? q : k;
#pragma unroll
    for (int nt = 0; nt < 4; ++nt) {
      int o = n0 + wn + nt * 16 + l15;
      float bl = bias[o];
      int h = o >> 6, d = o & 63;
#pragma unroll
      for (int mt = 0; mt < 4; ++mt)
#pragma unroll
        for (int r = 0; r < 4; ++r) {
          int token = m0 + wm + mt * 16 + quad * 4 + r;
          int b = token >> 11, s = token & 2047;
          dst[(size_t)(((b * 16 + h) * 2048) + s) * 64 + d] =
              f2bf((acc[mt][nt][r] + bl) * oscale);
        }
    }
  }
}

// ---------------- flash attention (key-parallel waves) ----------------
// 1024 blocks = 32 bh x 32 q-tiles of 64 rows; 2 waves. Each wave handles
// HALF the keys (wave w <-> keys [32w,32w+32) of each staged tile) for ALL
// four 16-query groups -> per-wave LDS reads halve vs query-split. The
// no-max softmax is linear, so li/accO are plain sums: one cross-wave
// reduction at kernel end through LDS. All register-array indices are
// compile-time constants (dynamic indexing demotes arrays to scratch!).
__global__ __launch_bounds__(128, 2) void attn_kernel(
    const ush* __restrict__ Q, const ush* __restrict__ K,
    const ush* __restrict__ VT, ush* __restrict__ O)
{
  const int bid = blockIdx.x;
  const int bh = (bid & 7) * 4 + (bid >> 8);   // same bh -> same XCD residue
  const int qt = (bid >> 3) & 31;
  const ush* qb = Q + (size_t)bh * 2048 * 64;
  const ush* kb = K + (size_t)bh * 2048 * 64;
  const ush* vtb = VT + (size_t)bh * 64 * 2048;   // [d][p(s)]
  const int t = threadIdx.x, w = t >> 6, lane = t & 63;
  const int l15 = lane & 15, quad = lane >> 4;
  const int q0 = qt * 64;                 // block's 64 queries (4 groups)

  __shared__ alignas(16) ush lK[2][64 * 64];     // [key][d], swizzled chunks
  __shared__ alignas(16) ush lV[2][64 * 64];     // [d][p(key)], swizzled chunks

  // staging: 512 chunks per tensor, 128 threads -> 4 chunks each.
  const int r0 = t >> 3;
  const int c0 = (t & 7) ^ (r0 & 7);
  const ush* kSrc = kb + (size_t)r0 * 64 + c0 * 8;      // +i*1024
  const ush* vSrc = vtb + (size_t)r0 * 2048 + c0 * 8;   // +i*16*2048

  // Q fragments (B-operand: n=q=l15, k=d), 4 groups x 2 kf
  bf16x8 qF[4][2];
#pragma unroll
  for (int g = 0; g < 4; ++g)
#pragma unroll
    for (int kf = 0; kf < 2; ++kf)
      qF[g][kf] = bc8(*(const u16x8*)(qb + (size_t)(q0 + g * 16 + l15) * 64 +
                                      kf * 32 + quad * 8));

  float li[4] = {0.f, 0.f, 0.f, 0.f};
  f32x4 accO[4][4];                       // O^T partial: [d][q], keys of wave w
#pragma unroll
  for (int g = 0; g < 4; ++g)
#pragma unroll
    for (int dt = 0; dt < 4; ++dt) accO[g][dt] = (f32x4){0.f, 0.f, 0.f, 0.f};

  // prologue: DMA tile 0 into buffer 0
#pragma unroll
  for (int i = 0; i < 4; ++i) {
    async16(kSrc + i * 1024, lK[0] + (i * 128 + t) * 8);
    async16(vSrc + (size_t)i * 16 * 2048, lV[0] + (i * 128 + t) * 8);
  }
  __syncthreads();                       // vmcnt drain = DMA complete

  for (int it = 0; it < 32; ++it) {
    const int cur = it & 1, nxt = cur ^ 1;
    if (it + 1 < 32) {                   // DMA next tile while computing this one
      const size_t ko = (size_t)(it + 1) * 64 * 64;   // K advances by rows
      const int vo = (it + 1) * 64;                   // V^T advances by cols
#pragma unroll
      for (int i = 0; i < 4; ++i) {
        async16(kSrc + ko + i * 1024, lK[nxt] + (i * 128 + t) * 8);
        async16(vSrc + vo + (size_t)i * 16 * 2048, lV[nxt] + (i * 128 + t) * 8);
      }
    }
    const ush* lk = lK[cur];
    const ush* lv = lV[cur];

    // S^T = K·Q^T, this wave's 32 keys: rows (2w+mt')*16+l15
    f32x4 sc[4][2];
#pragma unroll
    for (int g = 0; g < 4; ++g)
#pragma unroll
      for (int mt = 0; mt < 2; ++mt) sc[g][mt] = (f32x4){0.f, 0.f, 0.f, 0.f};
#pragma unroll
    for (int kf = 0; kf < 2; ++kf) {
#pragma unroll
      for (int mt = 0; mt < 2; ++mt) {
        int row = (2 * w + mt) * 16 + l15;
        bf16x8 aK = bc8(*(const u16x8*)(lk + row * 64 + (((kf * 4 + quad) ^ (row & 7)) * 8)));
#pragma unroll
        for (int g = 0; g < 4; ++g)
          sc[g][mt] = __builtin_amdgcn_mfma_f32_16x16x32_bf16(
              aK, qF[g][kf], sc[g][mt], 0, 0, 0);
      }
    }

    // softmax partials: raw v_exp (args bounded; K pre-scaled)
#pragma unroll
    for (int g = 0; g < 4; ++g) {
      float rs = 0.f;
#pragma unroll
      for (int mt = 0; mt < 2; ++mt)
#pragma unroll
        for (int r = 0; r < 4; ++r) {
          sc[g][mt][r] = __builtin_amdgcn_exp2f(sc[g][mt][r]);
          rs += sc[g][mt][r];
        }
      rs += __shfl_xor(rs, 16);
      rs += __shfl_xor(rs, 32);
      li[g] += rs;
    }

    // PV over this wave's key window (ks = w): A = V (contiguous b128 thanks
    // to the storage permutation), B = packed exps (in-register P^T).
    bf16x8 aV[4];
#pragma unroll
    for (int dt = 0; dt < 4; ++dt)
      aV[dt] = bc8(*(const u16x8*)(lv + (dt * 16 + l15) * 64 +
                                   (((w * 4 + quad) ^ (l15 & 7)) * 8)));
#pragma unroll
    for (int g = 0; g < 4; ++g) {
      u32x4 bw = { pack2bf_ru(sc[g][0][0], sc[g][0][1]),
                   pack2bf_ru(sc[g][0][2], sc[g][0][3]),
                   pack2bf_ru(sc[g][1][0], sc[g][1][1]),
                   pack2bf_ru(sc[g][1][2], sc[g][1][3]) };
      bf16x8 bP = __builtin_bit_cast(bf16x8, bw);
#pragma unroll
      for (int dt = 0; dt < 4; ++dt)
        accO[g][dt] = __builtin_amdgcn_mfma_f32_16x16x32_bf16(
            aV[dt], bP, accO[g][dt], 0, 0, 0);
    }
    __syncthreads();   // all reads of cur done + next-tile DMA drained
  }

  // cross-wave reduction with STATIC register indices: wave 0 owns groups
  // 0,1 and sends 2,3; wave 1 owns 2,3 and sends 0,1. LDS slot = group id.
  float* redO = (float*)lK;              // [g][dt][lane] f32x4 -> 16 KB
  float* redL = (float*)lV;              // [g][lane] float  -> 1 KB
#define SEND_GROUP(G)                                                        \
  {                                                                          \
    _Pragma("unroll")                                                        \
    for (int dt = 0; dt < 4; ++dt)                                           \
      *(f32x4*)(redO + (((G) * 4 + dt) * 64 + lane) * 4) = accO[G][dt];      \
    redL[(G) * 64 + lane] = li[G];                                           \
  }
  if (w == 0) { SEND_GROUP(2); SEND_GROUP(3); }
  else        { SEND_GROUP(0); SEND_GROUP(1); }
  __syncthreads();
  const int b = bh >> 4, h = bh & 15;
#define FINISH_GROUP(G)                                                      \
  {                                                                          \
    _Pragma("unroll")                                                        \
    for (int dt = 0; dt < 4; ++dt)                                           \
      accO[G][dt] += *(const f32x4*)(redO + (((G) * 4 + dt) * 64 + lane) * 4);\
    float lsum = li[G] + redL[(G) * 64 + lane];                              \
    const float linv = __builtin_amdgcn_rcpf(lsum);                          \
    const int s = q0 + (G) * 16 + l15;                                       \
    _Pragma("unroll")                                                        \
    for (int dt = 0; dt < 4; ++dt) {                                         \
      u16x4 pk = { f2bf(accO[G][dt][0] * linv), f2bf(accO[G][dt][1] * linv), \
                   f2bf(accO[G][dt][2] * linv), f2bf(accO[G][dt][3] * linv) };\
      *(u16x4*)(O + (size_t)(b * 2048 + s) * 1024 + h * 64 + dt * 16 +       \
                quad * 4) = pk;                                              \
    }                                                                        \
  }
  if (w == 0) { FINISH_GROUP(0); FINISH_GROUP(1); }
  else        { FINISH_GROUP(2); FINISH_GROUP(3); }
#undef SEND_GROUP
#undef FINISH_GROUP
}

// ---------------- output projection (fp32 out) ----------------
__global__ __launch_bounds__(256, 2) void out_gemm(
    const ush* __restrict__ ab, const ush* __restrict__ Wob,
    const float* __restrict__ bo, float* __restrict__ out)
{
  int rem = blockIdx.x;
  int m0 = (rem & 31) * 128;
  int n0 = (rem >> 5) * 128;
  __shared__ alignas(16) ush lA[128 * 64];
  __shared__ alignas(16) ush lB[128 * 64];
  f32x4 acc[4][4];
  gemm128_core(ab, Wob, m0, n0, lA, lB, acc);

  const int t = threadIdx.x, w = t >> 6, lane = t & 63;
  const int l15 = lane & 15, quad = lane >> 4;
  const int wm = (w >> 1) * 64, wn = (w & 1) * 64;
#pragma unroll
  for (int nt = 0; nt < 4; ++nt) {
    int o = n0 + wn + nt * 16 + l15;
    float bl = bo[o];
#pragma unroll
    for (int mt = 0; mt < 4; ++mt)
#pragma unroll
      for (int r = 0; r < 4; ++r) {
        int token = m0 + wm + mt * 16 + quad * 4 + r;
        out[(size_t)token * 1024 + o] = acc[mt][nt][r] + bl;
      }
  }
}

extern "C" void kernel_launch(void* const* d_in, const int* in_sizes, int n_in,
                              void* d_out, int out_size, void* d_ws, size_t ws_size,
                              hipStream_t stream)
{
  const float* x  = (const float*)d_in[0];
  const float* Wq = (const float*)d_in[1];
  const float* bq = (const float*)d_in[2];
  const float* Wk = (const float*)d_in[3];
  const float* bk = (const float*)d_in[4];
  const float* Wv = (const float*)d_in[5];
  const float* bv = (const float*)d_in[6];
  const float* Wo = (const float*)d_in[7];
  const float* bo = (const float*)d_in[8];
  float* out = (float*)d_out;

  char* ws = (char*)d_ws;
  ush* xb  = (ush*)(ws);                      // 8 MiB  [4096 x 1024]
  ush* Wqb = (ush*)(ws + (size_t)( 8u << 20));// 2 MiB each
  ush* Wkb = (ush*)(ws + (size_t)(10u << 20));
  ush* Wvb = (ush*)(ws + (size_t)(12u << 20));
  ush* Wob = (ush*)(ws + (size_t)(14u << 20));
  ush* qb  = (ush*)(ws + (size_t)(16u << 20));// 8 MiB [B,H,S,64]
  ush* kb  = (ush*)(ws + (size_t)(24u << 20));
  ush* vtb = (ush*)(ws + (size_t)(32u << 20));// 8 MiB [B,H,64,S] perm cols
  ush* ab  = (ush*)(ws + (size_t)(40u << 20));// 8 MiB [B,S,D] attn out (bf16)

  convert_kernel<<<8192, 256, 0, stream>>>(x, Wq, Wk, Wv, Wo,
                                           xb, Wqb, Wkb, Wvb, Wob);
  qkv_gemm<<<768, 256, 0, stream>>>(xb, Wqb, Wkb, Wvb, bq, bk, bv, qb, kb, vtb);
  attn_kernel<<<1024, 128, 0, stream>>>(qb, kb, vtb, ab);
  out_gemm<<<256, 256, 0, stream>>>(ab, Wob, bo, out);
}